// Round 5
// baseline (357.555 us; speedup 1.0000x reference)
//
#include <hip/hip_runtime.h>

// HemorrhageNet: per-row Poisson-binomial count distribution over 96 probs,
// truncated at 5, binned to severity[5] = {c0, c1+c2, c3+c4, c5, 0}.
//
// R5 strategy: PERSISTENT GRID-STRIDE + software pipeline, R2's lane layout.
//  - Evidence: R2 (shuffle), R3 (strided), R4 (LDS) all pinned at 124-139 us
//    with VALU work varying 4x -> time is a memory-system effect, not VALU
//    or coalescing. Wave-residency arithmetic: waves live ~12k cycles for
//    ~2-3k cycles of work -> queueing delay. All three kernels burst-issue
//    the whole grid's loads through short-lived waves; the 6.3 TB/s copy
//    ubench instead uses persistent grid-stride waves that PACE requests.
//  - R5 mimics the copy ubench exactly: 2048 blocks (= resident capacity at
//    <=64 VGPR), each wave sweeps 16 row-groups in address order, 2-stage
//    pipeline: issue next group's 3 float4 loads (one shared 32-bit voffset,
//    SGPR bases), compute current group, store, rotate.
//  - Lane layout (R2, proven): 8 lanes/row; thread t reads float4
//    #(g*256+t) of each array -> wave reads 4 KB contiguous per array.
//  - Compute: 12x 9-op STEP (a0..a4 only; exact for counts 0..4), then
//    butterfly d=1,2,4: 5 shuffles + 15 FMA/mul per round; c5 = 1 - sum
//    (mass conservation) once at the end. ~200 VALU instr/wave/iter.
//  - No LDS, no barriers. __launch_bounds__(256,8) -> <=64 VGPR,
//    32 waves/CU, grid exactly resident, zero tail.

#define THREADS 256
#define NGROUPS 32768          // 1048576 rows / 32 rows per group
#define GRID    2048           // 8 blocks/CU * 256 CU; 16 groups per block

__global__ __launch_bounds__(THREADS, 8) void hemorrhage_kernel(
    const float* __restrict__ x1,
    const float* __restrict__ x2,
    const float* __restrict__ x3,
    float* __restrict__ out)
{
    const int t = threadIdx.x;
    const int m = t & 7;                       // slot within row
    const int stride = gridDim.x;

    const float4* __restrict__ f1 = (const float4*)x1;
    const float4* __restrict__ f2 = (const float4*)x2;
    const float4* __restrict__ f3 = (const float4*)x3;

    int g = blockIdx.x;

    // ---- prologue: load group g ----
    unsigned idx = (unsigned)g * 256u + (unsigned)t;   // float4 index, <2^23
    float4 c1 = f1[idx];
    float4 c2 = f2[idx];
    float4 c3 = f3[idx];

    // truncated (deg<=4) Poisson-binomial step: 9 VALU ops/prob.
    // a4 = a4*(1-p) + a3*p is the EXACT P(count==4); mass >=5 untracked.
#define STEP(P)                              \
    do {                                     \
        const float p_ = (P);                \
        a4 = fmaf(p_, a3 - a4, a4);          \
        a3 = fmaf(p_, a2 - a3, a3);          \
        a2 = fmaf(p_, a1 - a2, a2);          \
        a1 = fmaf(p_, a0 - a1, a1);          \
        a0 = fmaf(-p_, a0, a0);              \
    } while (0)

    for (;;) {
        // ---- pipeline: issue next group's loads (wave-uniform branch) ----
        const int gn = g + stride;
        const bool have_next = (gn < NGROUPS);
        float4 n1, n2, n3;
        if (have_next) {
            const unsigned nidx = (unsigned)gn * 256u + (unsigned)t;
            n1 = f1[nidx];
            n2 = f2[nidx];
            n3 = f3[nidx];
        }

        // ---- local distribution over this lane's 12 probs ----
        float a0 = 1.0f, a1 = 0.0f, a2 = 0.0f, a3 = 0.0f, a4 = 0.0f;
        STEP(c1.x); STEP(c1.y); STEP(c1.z); STEP(c1.w);
        STEP(c2.x); STEP(c2.y); STEP(c2.z); STEP(c2.w);
        STEP(c3.x); STEP(c3.y); STEP(c3.z); STEP(c3.w);

        // ---- butterfly combine across the 8-lane group (5 values) ----
#pragma unroll
        for (int d = 1; d < 8; d <<= 1) {
            const float b0 = __shfl_xor(a0, d);
            const float b1 = __shfl_xor(a1, d);
            const float b2 = __shfl_xor(a2, d);
            const float b3 = __shfl_xor(a3, d);
            const float b4 = __shfl_xor(a4, d);

            float n0v = a0 * b0;
            float n1v = a0 * b1;
            n1v = fmaf(a1, b0, n1v);
            float n2v = a0 * b2;
            n2v = fmaf(a1, b1, n2v);
            n2v = fmaf(a2, b0, n2v);
            float n3v = a0 * b3;
            n3v = fmaf(a1, b2, n3v);
            n3v = fmaf(a2, b1, n3v);
            n3v = fmaf(a3, b0, n3v);
            float n4v = a0 * b4;
            n4v = fmaf(a1, b3, n4v);
            n4v = fmaf(a2, b2, n4v);
            n4v = fmaf(a3, b1, n4v);
            n4v = fmaf(a4, b0, n4v);

            a0 = n0v; a1 = n1v; a2 = n2v; a3 = n3v; a4 = n4v;
        }

        // ---- severity + store (lanes m<5: 160 contiguous B per wave-group) ----
        if (m < 5) {
            const float c5 = 1.0f - (((a0 + a1) + (a2 + a3)) + a4);
            float v;
            switch (m) {
                case 0: v = a0; break;
                case 1: v = a1 + a2; break;
                case 2: v = a3 + a4; break;
                case 3: v = c5; break;
                default: v = 0.0f; break;   // out is re-poisoned: must write zeros
            }
            const size_t row = (size_t)g * 32 + (t >> 3);
            out[row * 5 + m] = v;
        }

        if (!have_next) break;
        c1 = n1; c2 = n2; c3 = n3;
        g = gn;
    }
#undef STEP
}

extern "C" void kernel_launch(void* const* d_in, const int* in_sizes, int n_in,
                              void* d_out, int out_size, void* d_ws, size_t ws_size,
                              hipStream_t stream) {
    const float* x1 = (const float*)d_in[0];
    const float* x2 = (const float*)d_in[1];
    const float* x3 = (const float*)d_in[2];
    float* out = (float*)d_out;

    hemorrhage_kernel<<<GRID, THREADS, 0, stream>>>(x1, x2, x3, out);
}